// Round 1
// baseline (340.986 us; speedup 1.0000x reference)
//
#include <hip/hip_runtime.h>
#include <math.h>

typedef __attribute__((ext_vector_type(8))) short short8;
typedef __attribute__((ext_vector_type(4))) float f32x4;

#define CIN 66
#define BN_EPS 1e-5f

// haloed up-plane: 130 rows x 132 cols of u16 (1-row top/bottom, 2-col left/right halo)
#define PLROW 132
#define PLN   17160            /* 130*132 u16 per (b,oc) plane; 512 planes = 17.57 MB */

// ---- ws layout ----
// u16   [0, 512*PLN)        up (bf16) haloed planes
// float [CO_F, +1048576)    coord-channel output field co[64][16384] (fp32)
// u16   [BSQ_U16, +BSQ_CNT) squeeze-B fragment stream
// u16   [BF_U16, +BF_CNT)   fused-B fragment stream (18 ks * 4 nt, K=576)
// float [SC_F,+594) scale, [SH_F,+594) shift
#define CO_F     ((size_t)4500000)
#define BSQ_U16  ((size_t)16777216)
#define BSQ_CNT  32768                /* 8 kc * 8 nt * 64 * 8 */
#define BF_U16   (BSQ_U16 + BSQ_CNT)
#define BF_CNT   36864                /* 18 ks * 4 nt * 64 * 8 */
#define SC_F     ((size_t)8424448)
#define SH_F     (SC_F + 594)

// precise RNE (prep only)
static __device__ __forceinline__ unsigned short f2bf(float f) {
    unsigned u = __float_as_uint(f);
    u += 0x7fffu + ((u >> 16) & 1u);
    return (unsigned short)(u >> 16);
}
// fast pack: round-half-up + v_perm_b32
static __device__ __forceinline__ unsigned pack2(float lo, float hi) {
    return __builtin_amdgcn_perm(__float_as_uint(hi) + 0x8000u,
                                 __float_as_uint(lo) + 0x8000u, 0x07060302u);
}

// ------------------------------------------------------------------
// prep: BN fold + B streams + halo zero + coord-channel field
// ------------------------------------------------------------------
__global__ void prep_kernel(const float* __restrict__ w_squeeze,
                            const float* __restrict__ gamma,
                            const float* __restrict__ beta,
                            const float* __restrict__ mean,
                            const float* __restrict__ var,
                            const float* __restrict__ w_gw,
                            const float* __restrict__ w_gf,
                            const float* __restrict__ w_conv,
                            float* __restrict__ ws)
{
    unsigned short* wsu = (unsigned short*)ws;
    const int tid = blockIdx.x * blockDim.x + threadIdx.x;
    const int nth = gridDim.x * blockDim.x;

    for (int idx = tid; idx < BSQ_CNT; idx += nth) {
        int j = idx & 7, lane = (idx >> 3) & 63, r = idx >> 9;
        int nt = r & 7, kc = r >> 3;
        int k = kc * 32 + ((lane >> 4) << 3) + j;
        int n = nt * 16 + (lane & 15);
        wsu[BSQ_U16 + idx] = f2bf(w_squeeze[n * 256 + k]);
    }
    // fused B stream: channels 0..63 only (coord channels precomputed below)
    for (int idx = tid; idx < BF_CNT; idx += nth) {
        int j = idx & 7, lane = (idx >> 3) & 63, r = idx >> 9;
        int nt = r & 3, ks = r >> 2;
        int k = ks * 32 + ((lane >> 4) << 3) + j;   // 0..575 always
        int n = nt * 16 + (lane & 15);
        wsu[BF_U16 + idx] = f2bf(w_conv[n * 594 + k]);
    }
    for (int i = tid; i < CIN * 9; i += nth) {
        float sc = gamma[i] / sqrtf(var[i] + BN_EPS);
        ws[SC_F + i] = sc;
        ws[SH_F + i] = beta[i] - mean[i] * sc;
    }
    // zero halo of all 512 planes: 388 u32 per plane
    // top row u32[0,66), bottom row u32[8514,8580), sides rows 1..128: u32 r*66 and r*66+65
    for (int idx = tid; idx < 512 * 388; idx += nth) {
        int plane = idx / 388, r = idx - plane * 388;
        unsigned* pb = (unsigned*)(wsu + (size_t)plane * PLN);
        if (r < 66)       pb[r] = 0u;
        else if (r < 132) pb[8514 + (r - 66)] = 0u;
        else {
            int rr = (r - 132) >> 1, side = (r - 132) & 1;
            pb[(rr + 1) * 66 + (side ? 65 : 0)] = 0u;
        }
    }
    // coordinate-channel contribution field (input-independent, exact fp32)
    if (tid < 16384) {
        const int h = tid >> 7, w = tid & 127;
        float fsA[9], fsB[9];
#pragma unroll
        for (int c = 0; c < 2; ++c) {
            const int cu = 64 + c;
            float n[9];
#pragma unroll
            for (int dy = 0; dy < 3; ++dy)
#pragma unroll
                for (int dx = 0; dx < 3; ++dx) {
                    const int gy = h - 1 + dy, gx = w - 1 + dx;
                    const bool ok = ((unsigned)gy < 128u) & ((unsigned)gx < 128u);
                    const float v = (c == 0) ? (gx * (2.f / 127.f) - 1.f)
                                             : (gy * (2.f / 127.f) - 1.f);
                    n[dy * 3 + dx] = ok ? v : 0.f;
                }
            const float p = (n[0]+n[1]+n[2]+n[3]+n[4]+n[5]+n[6]+n[7]+n[8]) * (1.f/9.f);
            const float* gw = w_gw + cu * 9;
            const float* gf = w_gf + cu * 81;
            float e[9], se = 0.f;
#pragma unroll
            for (int j = 0; j < 9; ++j) { e[j] = __expf(p * gw[j]); se += e[j]; }
            const float sinv = 1.f / se;
            float* fs = c ? fsB : fsA;
#pragma unroll
            for (int j = 0; j < 9; ++j) {
                float cv = 0.f;
#pragma unroll
                for (int i = 0; i < 9; ++i) cv = fmaf(n[i], gf[j * 9 + i], cv);
                const float sc = gamma[cu * 9 + j] / sqrtf(var[cu * 9 + j] + BN_EPS);
                const float sh = beta[cu * 9 + j] - mean[cu * 9 + j] * sc;
                const float f = fmaf(cv, sc, sh);
                fs[j] = fmaxf(f, 0.f) * (e[j] * sinv);
            }
        }
#pragma unroll 1
        for (int oc = 0; oc < 64; ++oc) {
            const float* wc = w_conv + oc * 594;
            float s = 0.f;
#pragma unroll
            for (int j = 0; j < 9; ++j)
                s = fmaf(fsA[j], wc[576 + j], fmaf(fsB[j], wc[585 + j], s));
            ws[CO_F + (size_t)oc * 16384 + tid] = s;
        }
    }
}

// ------------------------------------------------------------------
// squeeze: space-to-depth + 1x1 conv as bf16 MFMA GEMM
// XCD-swizzled (batch b -> XCD b), pipelined B (low VGPR), haloed up-write
// ------------------------------------------------------------------
__global__ __launch_bounds__(256, 5) void squeeze_mfma(
    const float* __restrict__ x,
    float* __restrict__ wsp,
    float* __restrict__ out)
{
    __shared__ uint4 As[32 * 64];   // 32768 B -> 5 blocks/CU

    const int bx  = blockIdx.x;
    const int b   = bx & 7;         // batch -> XCD affinity
    const int pos = bx >> 3;        // 0..255
    const int h   = pos >> 1;
    const int w0  = (pos & 1) * 64;
    const int tid  = threadIdx.x;
    const int lane = tid & 63;
    const int wv   = tid >> 6;
    const int oct = tid >> 5;       // 0..7
    const int pp  = tid & 31;       // pixel pair

    // ---- A loads: 16 float4, all issued up front ----
    float4 v[2][8];
#pragma unroll
    for (int gy = 0; gy < 2; ++gy)
#pragma unroll
        for (int i = 0; i < 8; ++i)
            v[gy][i] = *(const float4*)(x +
                (size_t)(b * 64 + oct * 8 + i) * 65536 +
                (2 * h + gy) * 256 + 2 * w0 + 4 * pp);

    // ---- pack to fragment rows: row r=(gy+2*gx)*8+oct, pixel 2pp+p ----
#pragma unroll
    for (int gy = 0; gy < 2; ++gy)
#pragma unroll
        for (int gx = 0; gx < 2; ++gx)
#pragma unroll
            for (int p = 0; p < 2; ++p) {
                const int comp = p * 2 + gx;
                uint4 u;
                u.x = pack2(((const float*)&v[gy][0])[comp], ((const float*)&v[gy][1])[comp]);
                u.y = pack2(((const float*)&v[gy][2])[comp], ((const float*)&v[gy][3])[comp]);
                u.z = pack2(((const float*)&v[gy][4])[comp], ((const float*)&v[gy][5])[comp]);
                u.w = pack2(((const float*)&v[gy][6])[comp], ((const float*)&v[gy][7])[comp]);
                As[((gy + 2 * gx) * 8 + oct) * 64 + 2 * pp + p] = u;
            }

    __syncthreads();

    // ---- MFMA: software-pipelined B loads (16 regs instead of 64) ----
    const unsigned short* bsq = (const unsigned short*)wsp + BSQ_U16;
    const int q = lane >> 4, m = lane & 15;
    f32x4 acc[4][2];
#pragma unroll
    for (int mt = 0; mt < 4; ++mt)
#pragma unroll
        for (int j = 0; j < 2; ++j) acc[mt][j] = (f32x4){0.f, 0.f, 0.f, 0.f};

    short8 b0 = *(const short8*)(bsq + (size_t)((2 * wv + 0) * 64 + lane) * 8);
    short8 b1 = *(const short8*)(bsq + (size_t)((2 * wv + 1) * 64 + lane) * 8);
#pragma unroll
    for (int ks = 0; ks < 8; ++ks) {
        short8 nb0, nb1;
        if (ks < 7) {
            nb0 = *(const short8*)(bsq + (size_t)(((ks + 1) * 8 + 2 * wv + 0) * 64 + lane) * 8);
            nb1 = *(const short8*)(bsq + (size_t)(((ks + 1) * 8 + 2 * wv + 1) * 64 + lane) * 8);
        }
#pragma unroll
        for (int mt = 0; mt < 4; ++mt) {
            short8 a = *(const short8*)&As[(ks * 4 + q) * 64 + mt * 16 + m];
            acc[mt][0] = __builtin_amdgcn_mfma_f32_16x16x32_bf16(a, b0, acc[mt][0], 0, 0, 0);
            acc[mt][1] = __builtin_amdgcn_mfma_f32_16x16x32_bf16(a, b1, acc[mt][1], 0, 0, 0);
        }
        if (ks < 7) { b0 = nb0; b1 = nb1; }
    }

    // ---- epilogue: waves 0,1 -> up (bf16, haloed); waves 2,3 -> out (fp32) ----
    if (wv < 2) {
        unsigned short* upw = (unsigned short*)wsp;
#pragma unroll
        for (int j = 0; j < 2; ++j) {
            const int oc = (2 * wv + j) * 16 + m;
#pragma unroll
            for (int mt = 0; mt < 4; ++mt) {
                uint2 st;
                st.x = pack2(acc[mt][j][0], acc[mt][j][1]);
                st.y = pack2(acc[mt][j][2], acc[mt][j][3]);
                *(uint2*)(upw + (size_t)(b * 64 + oc) * PLN + (size_t)(h + 1) * PLROW
                          + (w0 + mt * 16 + q * 4 + 2)) = st;
            }
        }
    } else {
#pragma unroll
        for (int j = 0; j < 2; ++j) {
            const int oc = (2 * wv + j) * 16 + m;
            const int lc = oc - 64;
            const int ch = (lc & 1) ? (96 + ((lc - 1) >> 1)) : (32 + (lc >> 1));
#pragma unroll
            for (int mt = 0; mt < 4; ++mt) {
                float4 st = {acc[mt][j][0], acc[mt][j][1], acc[mt][j][2], acc[mt][j][3]};
                *(float4*)(out + ((size_t)(b * 128 + ch) * 128 + h) * 128
                           + (w0 + mt * 16 + q * 4)) = st;
            }
        }
    }
}

// ------------------------------------------------------------------
// fused helpers
// ------------------------------------------------------------------
__device__ __forceinline__ void fs_from_n(
    int cu, const float n[9],
    const float* __restrict__ w_gw, const float* __restrict__ w_gf,
    const float* __restrict__ scp, const float* __restrict__ shp,
    float fs[9])
{
    const float p = (n[0] + n[1] + n[2] + n[3] + n[4] + n[5] + n[6] + n[7] + n[8]) * (1.f / 9.f);
    const float* gw = w_gw + cu * 9;
    const float* gf = w_gf + cu * 81;
    const float* sc = scp + cu * 9;
    const float* sh = shp + cu * 9;
    float e[9], se = 0.f;
#pragma unroll
    for (int j = 0; j < 9; ++j) { e[j] = __expf(p * gw[j]); se += e[j]; }
    const float sinv = 1.f / se;
#pragma unroll
    for (int j = 0; j < 9; ++j) {
        float cv = n[0] * gf[j * 9 + 0];
        cv = fmaf(n[1], gf[j * 9 + 1], cv); cv = fmaf(n[2], gf[j * 9 + 2], cv);
        cv = fmaf(n[3], gf[j * 9 + 3], cv); cv = fmaf(n[4], gf[j * 9 + 4], cv);
        cv = fmaf(n[5], gf[j * 9 + 5], cv); cv = fmaf(n[6], gf[j * 9 + 6], cv);
        cv = fmaf(n[7], gf[j * 9 + 7], cv); cv = fmaf(n[8], gf[j * 9 + 8], cv);
        float f = fmaf(cv, sc[j], sh[j]);
        fs[j] = fmaxf(f, 0.f) * (e[j] * sinv);
    }
}

__device__ __forceinline__ void pack_into(unsigned* pk, int ci, const float fs[9], float& carry)
{
    const int off = 9 * ci;
    if ((ci & 1) == 0) {
#pragma unroll
        for (int t = 0; t < 4; ++t) pk[off / 2 + t] = pack2(fs[2 * t], fs[2 * t + 1]);
        carry = fs[8];
    } else {
        pk[(off - 1) / 2] = pack2(carry, fs[0]);
#pragma unroll
        for (int t = 0; t < 4; ++t) pk[(off + 1) / 2 + t] = pack2(fs[1 + 2 * t], fs[2 + 2 * t]);
    }
}

// issue all 24 row-loads (8 ch x 3 rows) up front; halo layout -> no border path
__device__ __forceinline__ void chunk_loads(
    int cbase, int lane, int h0, int w0,
    const unsigned short* __restrict__ upb, uint2 vr[8][3])
{
    const int px = lane & 7, py = lane >> 3;
    // storage row of (gy0 = h0+py-1) is h0+py; storage col base (w0+px+1)&~1 (even)
    const size_t rowoff = (size_t)(h0 + py) * PLROW + (size_t)((w0 + px + 1) & ~1);
#pragma unroll
    for (int ci = 0; ci < 8; ++ci) {
        const int cu = __builtin_amdgcn_readfirstlane(cbase + ci);
        const unsigned short* cb = upb + (size_t)cu * PLN + rowoff;
#pragma unroll
        for (int dy = 0; dy < 3; ++dy)
            vr[ci][dy] = *(const uint2*)(cb + dy * PLROW);
    }
}

__device__ __forceinline__ void chunk_compute(
    int cbase, int lane, const uint2 vr[8][3],
    const float* __restrict__ w_gw, const float* __restrict__ w_gf,
    const float* __restrict__ scp, const float* __restrict__ shp,
    unsigned pk[36])
{
    const unsigned sh = (lane & 1) ? 0u : 16u;   // parity of gxc == parity of lane
    float carry = 0.f;
#pragma unroll
    for (int ci = 0; ci < 8; ++ci) {
        const int cu = __builtin_amdgcn_readfirstlane(cbase + ci);
        float n[9];
#pragma unroll
        for (int dy = 0; dy < 3; ++dy) {
            const uint2 vv = vr[ci][dy];
            unsigned long long t = (((unsigned long long)vv.y) << 32) | vv.x;
            t >>= sh;
            n[dy * 3 + 0] = __uint_as_float((unsigned)t << 16);
            n[dy * 3 + 1] = __uint_as_float((unsigned)t & 0xffff0000u);
            n[dy * 3 + 2] = __uint_as_float((unsigned)(t >> 32) << 16);
        }
        float fs[9];
        fs_from_n(cu, n, w_gw, w_gf, scp, shp, fs);
        pack_into(pk, ci, fs, carry);
    }
}

template<int NSTEPS>
__device__ __forceinline__ void do_mfma(
    int base, const uint4* As, const unsigned short* __restrict__ bfw,
    int wv, int lane, f32x4 acc[2][2])
{
    const int q = lane >> 4, m = lane & 15;
    const int ntb = (wv >> 1) * 2;
    const int pt0 = (wv & 1) * 2;
#pragma unroll
    for (int ks = 0; ks < NSTEPS; ++ks) {
        short8 b0 = *(const short8*)(bfw + (size_t)(((base + ks) * 4 + ntb + 0) * 64 + lane) * 8);
        short8 b1 = *(const short8*)(bfw + (size_t)(((base + ks) * 4 + ntb + 1) * 64 + lane) * 8);
#pragma unroll
        for (int mt = 0; mt < 2; ++mt) {
            short8 a = *(const short8*)&As[(ks * 4 + q) * 64 + (pt0 + mt) * 16 + m];
            acc[mt][0] = __builtin_amdgcn_mfma_f32_16x16x32_bf16(a, b0, acc[mt][0], 0, 0, 0);
            acc[mt][1] = __builtin_amdgcn_mfma_f32_16x16x32_bf16(a, b1, acc[mt][1], 0, 0, 0);
        }
    }
}

// ------------------------------------------------------------------
// fused: XCD-swizzled, haloed up (no border path), prefetched loads,
// coord channels folded into precomputed co-field, K=576 (2x9 ks)
// ------------------------------------------------------------------
__global__ __launch_bounds__(256, 4) void fused_mfma(
    const float* __restrict__ wsp,
    const float* __restrict__ w_gw,
    const float* __restrict__ w_gf,
    const float* __restrict__ b_conv,
    float* __restrict__ out)
{
    __shared__ uint4 As[36 * 64];   // 36864 B

    const int bx = blockIdx.x;
    const int b  = bx & 7;          // batch -> XCD affinity
    const int t  = bx >> 3;
    const int w0 = (t & 15) * 8;
    const int h0 = ((t >> 4) & 15) * 8;
    const int tid = threadIdx.x, lane = tid & 63, wv = tid >> 6;

    const unsigned short* upb = (const unsigned short*)wsp + (size_t)b * 64 * PLN;
    const float* scp = wsp + SC_F;
    const float* shp = wsp + SH_F;
    const unsigned short* bfw = (const unsigned short*)wsp + BF_U16;

    f32x4 acc[2][2];
#pragma unroll
    for (int mt = 0; mt < 2; ++mt)
#pragma unroll
        for (int j = 0; j < 2; ++j) acc[mt][j] = (f32x4){0.f, 0.f, 0.f, 0.f};

    uint2 vr[8][3];
    unsigned pk[36];

    // ================= chunk 0 : channels 0..31 =================
    chunk_loads(8 * wv, lane, h0, w0, upb, vr);
    chunk_compute(8 * wv, lane, vr, w_gw, w_gf, scp, shp, pk);
#pragma unroll
    for (int kb = 0; kb < 9; ++kb)
        As[(9 * wv + kb) * 64 + lane] =
            (uint4){pk[4 * kb], pk[4 * kb + 1], pk[4 * kb + 2], pk[4 * kb + 3]};
    __syncthreads();

    // ================= chunk 1 : channels 32..63 =================
    chunk_loads(32 + 8 * wv, lane, h0, w0, upb, vr);   // in flight under MFMA0
    do_mfma<9>(0, As, bfw, wv, lane, acc);
    chunk_compute(32 + 8 * wv, lane, vr, w_gw, w_gf, scp, shp, pk);
    __syncthreads();   // all waves done reading As (chunk-0 MFMA)
#pragma unroll
    for (int kb = 0; kb < 9; ++kb)
        As[(9 * wv + kb) * 64 + lane] =
            (uint4){pk[4 * kb], pk[4 * kb + 1], pk[4 * kb + 2], pk[4 * kb + 3]};
    __syncthreads();
    do_mfma<9>(9, As, bfw, wv, lane, acc);

    // ================= epilogue: + bias + coord field, float4 stores =================
    const int q = lane >> 4, m = lane & 15;
    const int ntb = (wv >> 1) * 2, pt0 = (wv & 1) * 2;
    const float* co = wsp + CO_F;
#pragma unroll
    for (int mt = 0; mt < 2; ++mt)
#pragma unroll
        for (int j = 0; j < 2; ++j) {
            const int oc = (ntb + j) * 16 + m;
            const int ch = (oc & 1) ? (64 + (oc >> 1)) : (oc >> 1);
            const int row = h0 + (pt0 + mt) * 2 + (q >> 1);
            const int col = w0 + (q & 1) * 4;
            const size_t pix = (size_t)row * 128 + col;
            const float4 cv = *(const float4*)(co + (size_t)oc * 16384 + pix);
            const float bias = b_conv[oc];
            float4 st = { acc[mt][j][0] + bias + cv.x,
                          acc[mt][j][1] + bias + cv.y,
                          acc[mt][j][2] + bias + cv.z,
                          acc[mt][j][3] + bias + cv.w };
            *(float4*)(out + (size_t)(b * 128 + ch) * 16384 + pix) = st;
        }
}

// ------------------------------------------------------------------
extern "C" void kernel_launch(void* const* d_in, const int* in_sizes, int n_in,
                              void* d_out, int out_size, void* d_ws, size_t ws_size,
                              hipStream_t stream)
{
    const float* x         = (const float*)d_in[0];
    const float* w_squeeze = (const float*)d_in[1];
    const float* w_gw      = (const float*)d_in[2];
    const float* w_gf      = (const float*)d_in[3];
    const float* gamma     = (const float*)d_in[4];
    const float* beta      = (const float*)d_in[5];
    const float* mean      = (const float*)d_in[6];
    const float* var       = (const float*)d_in[7];
    const float* w_conv    = (const float*)d_in[8];
    const float* b_conv    = (const float*)d_in[9];
    float* out = (float*)d_out;
    float* ws  = (float*)d_ws;

    prep_kernel<<<160, 256, 0, stream>>>(w_squeeze, gamma, beta, mean, var,
                                         w_gw, w_gf, w_conv, ws);
    squeeze_mfma<<<2048, 256, 0, stream>>>(x, ws, out);
    fused_mfma<<<2048, 256, 0, stream>>>(ws, w_gw, w_gf, b_conv, out);
}

// Round 2
// 334.134 us; speedup vs baseline: 1.0205x; 1.0205x over previous
//
#include <hip/hip_runtime.h>
#include <math.h>

typedef __attribute__((ext_vector_type(8))) short short8;
typedef __attribute__((ext_vector_type(4))) float f32x4;

#define CIN 66
#define BN_EPS 1e-5f

// haloed up-plane: 130 rows x 136 cols of u16
// (1-row top/bottom halo, 4-col left halo, interior cols [4,132), right pad)
// row pitch 272 B (8B-aligned); interior col w -> storage col w+4 (8B-aligned uint2 stores)
#define PLROW 136
#define PLN   17680            /* 130*136 u16 per (b,oc) plane; 512 planes = 18.1 MB */

// ---- ws layout ----
// u16   [0, 512*PLN)        up (bf16) haloed planes           (ends at float 4,526,080)
// float [CO_F, +1048576)    coord-channel output field co[64][16384] (fp32)
// u16   [BSQ_U16, +BSQ_CNT) squeeze-B fragment stream
// u16   [BF_U16, +BF_CNT)   fused-B fragment stream (18 ks * 4 nt, K=576)
// float [SC_F,+594) scale, [SH_F,+594) shift
#define CO_F     ((size_t)4587520)
#define BSQ_U16  ((size_t)16777216)
#define BSQ_CNT  32768                /* 8 kc * 8 nt * 64 * 8 */
#define BF_U16   (BSQ_U16 + BSQ_CNT)
#define BF_CNT   36864                /* 18 ks * 4 nt * 64 * 8 */
#define SC_F     ((size_t)8424448)
#define SH_F     (SC_F + 594)

// precise RNE (prep only)
static __device__ __forceinline__ unsigned short f2bf(float f) {
    unsigned u = __float_as_uint(f);
    u += 0x7fffu + ((u >> 16) & 1u);
    return (unsigned short)(u >> 16);
}
// fast pack: round-half-up + v_perm_b32
static __device__ __forceinline__ unsigned pack2(float lo, float hi) {
    return __builtin_amdgcn_perm(__float_as_uint(hi) + 0x8000u,
                                 __float_as_uint(lo) + 0x8000u, 0x07060302u);
}

// ------------------------------------------------------------------
// prep: BN fold + B streams + halo zero + coord-channel field
// grid MUST be 256 blocks x 256 threads (co-field uses all 65536 threads)
// ------------------------------------------------------------------
__global__ void prep_kernel(const float* __restrict__ w_squeeze,
                            const float* __restrict__ gamma,
                            const float* __restrict__ beta,
                            const float* __restrict__ mean,
                            const float* __restrict__ var,
                            const float* __restrict__ w_gw,
                            const float* __restrict__ w_gf,
                            const float* __restrict__ w_conv,
                            float* __restrict__ ws)
{
    unsigned short* wsu = (unsigned short*)ws;
    const int tid = blockIdx.x * blockDim.x + threadIdx.x;
    const int nth = gridDim.x * blockDim.x;

    for (int idx = tid; idx < BSQ_CNT; idx += nth) {
        int j = idx & 7, lane = (idx >> 3) & 63, r = idx >> 9;
        int nt = r & 7, kc = r >> 3;
        int k = kc * 32 + ((lane >> 4) << 3) + j;
        int n = nt * 16 + (lane & 15);
        wsu[BSQ_U16 + idx] = f2bf(w_squeeze[n * 256 + k]);
    }
    // fused B stream: channels 0..63 only (coord channels precomputed below)
    for (int idx = tid; idx < BF_CNT; idx += nth) {
        int j = idx & 7, lane = (idx >> 3) & 63, r = idx >> 9;
        int nt = r & 3, ks = r >> 2;
        int k = ks * 32 + ((lane >> 4) << 3) + j;   // 0..575 always
        int n = nt * 16 + (lane & 15);
        wsu[BF_U16 + idx] = f2bf(w_conv[n * 594 + k]);
    }
    for (int i = tid; i < CIN * 9; i += nth) {
        float sc = gamma[i] / sqrtf(var[i] + BN_EPS);
        ws[SC_F + i] = sc;
        ws[SH_F + i] = beta[i] - mean[i] * sc;
    }
    // zero halo of all 512 planes: 648 u32 per plane
    // top row u32[0,68), bottom row u32 base 129*68=8772, sides rows 1..128:
    // u32 {0,1} (left) and {66,67} (right) per row
    for (int idx = tid; idx < 512 * 648; idx += nth) {
        int plane = idx / 648, r = idx - plane * 648;
        unsigned* pb = (unsigned*)(wsu + (size_t)plane * PLN);
        if (r < 68)       pb[r] = 0u;
        else if (r < 136) pb[8772 + (r - 68)] = 0u;
        else {
            int rr = (r - 136) >> 2, k = (r - 136) & 3;
            pb[(rr + 1) * 68 + (k < 2 ? k : 64 + k)] = 0u;
        }
    }
    // coordinate-channel contribution field (input-independent, exact fp32)
    // 65536 threads: pix = tid&16383, oc-group g = tid>>14 handles 16 ocs
    if (tid < 65536) {
        const int pix = tid & 16383;
        const int g   = tid >> 14;
        const int h = pix >> 7, w = pix & 127;
        float fsA[9], fsB[9];
#pragma unroll
        for (int c = 0; c < 2; ++c) {
            const int cu = 64 + c;
            float n[9];
#pragma unroll
            for (int dy = 0; dy < 3; ++dy)
#pragma unroll
                for (int dx = 0; dx < 3; ++dx) {
                    const int gy = h - 1 + dy, gx = w - 1 + dx;
                    const bool ok = ((unsigned)gy < 128u) & ((unsigned)gx < 128u);
                    const float v = (c == 0) ? (gx * (2.f / 127.f) - 1.f)
                                             : (gy * (2.f / 127.f) - 1.f);
                    n[dy * 3 + dx] = ok ? v : 0.f;
                }
            const float p = (n[0]+n[1]+n[2]+n[3]+n[4]+n[5]+n[6]+n[7]+n[8]) * (1.f/9.f);
            const float* gw = w_gw + cu * 9;
            const float* gf = w_gf + cu * 81;
            float e[9], se = 0.f;
#pragma unroll
            for (int j = 0; j < 9; ++j) { e[j] = __expf(p * gw[j]); se += e[j]; }
            const float sinv = 1.f / se;
            float* fs = c ? fsB : fsA;
#pragma unroll
            for (int j = 0; j < 9; ++j) {
                float cv = 0.f;
#pragma unroll
                for (int i = 0; i < 9; ++i) cv = fmaf(n[i], gf[j * 9 + i], cv);
                const float sc = gamma[cu * 9 + j] / sqrtf(var[cu * 9 + j] + BN_EPS);
                const float sh = beta[cu * 9 + j] - mean[cu * 9 + j] * sc;
                const float f = fmaf(cv, sc, sh);
                fs[j] = fmaxf(f, 0.f) * (e[j] * sinv);
            }
        }
#pragma unroll 1
        for (int oc = g * 16; oc < g * 16 + 16; ++oc) {
            const float* wc = w_conv + oc * 594;
            float s = 0.f;
#pragma unroll
            for (int j = 0; j < 9; ++j)
                s = fmaf(fsA[j], wc[576 + j], fmaf(fsB[j], wc[585 + j], s));
            ws[CO_F + (size_t)oc * 16384 + pix] = s;
        }
    }
}

// ------------------------------------------------------------------
// squeeze: space-to-depth + 1x1 conv as bf16 MFMA GEMM
// XCD-swizzled (batch b -> XCD b), pipelined B, haloed aligned up-write
// ------------------------------------------------------------------
__global__ __launch_bounds__(256, 4) void squeeze_mfma(
    const float* __restrict__ x,
    float* __restrict__ wsp,
    float* __restrict__ out)
{
    __shared__ uint4 As[32 * 64];   // 32768 B

    const int bx  = blockIdx.x;
    const int b   = bx & 7;         // batch -> XCD affinity
    const int pos = bx >> 3;        // 0..255
    const int h   = pos >> 1;
    const int w0  = (pos & 1) * 64;
    const int tid  = threadIdx.x;
    const int lane = tid & 63;
    const int wv   = tid >> 6;
    const int oct = tid >> 5;       // 0..7
    const int pp  = tid & 31;       // pixel pair

    // ---- A loads: 16 float4, all issued up front ----
    float4 v[2][8];
#pragma unroll
    for (int gy = 0; gy < 2; ++gy)
#pragma unroll
        for (int i = 0; i < 8; ++i)
            v[gy][i] = *(const float4*)(x +
                (size_t)(b * 64 + oct * 8 + i) * 65536 +
                (2 * h + gy) * 256 + 2 * w0 + 4 * pp);

    // ---- pack to fragment rows: row r=(gy+2*gx)*8+oct, pixel 2pp+p ----
#pragma unroll
    for (int gy = 0; gy < 2; ++gy)
#pragma unroll
        for (int gx = 0; gx < 2; ++gx)
#pragma unroll
            for (int p = 0; p < 2; ++p) {
                const int comp = p * 2 + gx;
                uint4 u;
                u.x = pack2(((const float*)&v[gy][0])[comp], ((const float*)&v[gy][1])[comp]);
                u.y = pack2(((const float*)&v[gy][2])[comp], ((const float*)&v[gy][3])[comp]);
                u.z = pack2(((const float*)&v[gy][4])[comp], ((const float*)&v[gy][5])[comp]);
                u.w = pack2(((const float*)&v[gy][6])[comp], ((const float*)&v[gy][7])[comp]);
                As[((gy + 2 * gx) * 8 + oct) * 64 + 2 * pp + p] = u;
            }

    // ---- first B fragments in flight under the barrier ----
    const unsigned short* bsq = (const unsigned short*)wsp + BSQ_U16;
    short8 b0 = *(const short8*)(bsq + (size_t)((2 * wv + 0) * 64 + lane) * 8);
    short8 b1 = *(const short8*)(bsq + (size_t)((2 * wv + 1) * 64 + lane) * 8);

    __syncthreads();

    // ---- MFMA: software-pipelined B loads ----
    const int q = lane >> 4, m = lane & 15;
    f32x4 acc[4][2];
#pragma unroll
    for (int mt = 0; mt < 4; ++mt)
#pragma unroll
        for (int j = 0; j < 2; ++j) acc[mt][j] = (f32x4){0.f, 0.f, 0.f, 0.f};

#pragma unroll
    for (int ks = 0; ks < 8; ++ks) {
        short8 nb0, nb1;
        if (ks < 7) {
            nb0 = *(const short8*)(bsq + (size_t)(((ks + 1) * 8 + 2 * wv + 0) * 64 + lane) * 8);
            nb1 = *(const short8*)(bsq + (size_t)(((ks + 1) * 8 + 2 * wv + 1) * 64 + lane) * 8);
        }
#pragma unroll
        for (int mt = 0; mt < 4; ++mt) {
            short8 a = *(const short8*)&As[(ks * 4 + q) * 64 + mt * 16 + m];
            acc[mt][0] = __builtin_amdgcn_mfma_f32_16x16x32_bf16(a, b0, acc[mt][0], 0, 0, 0);
            acc[mt][1] = __builtin_amdgcn_mfma_f32_16x16x32_bf16(a, b1, acc[mt][1], 0, 0, 0);
        }
        if (ks < 7) { b0 = nb0; b1 = nb1; }
    }

    // ---- epilogue: waves 0,1 -> up (bf16, haloed); waves 2,3 -> out (fp32) ----
    if (wv < 2) {
        unsigned short* upw = (unsigned short*)wsp;
#pragma unroll
        for (int j = 0; j < 2; ++j) {
            const int oc = (2 * wv + j) * 16 + m;
#pragma unroll
            for (int mt = 0; mt < 4; ++mt) {
                uint2 st;
                st.x = pack2(acc[mt][j][0], acc[mt][j][1]);
                st.y = pack2(acc[mt][j][2], acc[mt][j][3]);
                *(uint2*)(upw + (size_t)(b * 64 + oc) * PLN + (size_t)(h + 1) * PLROW
                          + (w0 + mt * 16 + q * 4 + 4)) = st;
            }
        }
    } else {
#pragma unroll
        for (int j = 0; j < 2; ++j) {
            const int oc = (2 * wv + j) * 16 + m;
            const int lc = oc - 64;
            const int ch = (lc & 1) ? (96 + ((lc - 1) >> 1)) : (32 + (lc >> 1));
#pragma unroll
            for (int mt = 0; mt < 4; ++mt) {
                float4 st = {acc[mt][j][0], acc[mt][j][1], acc[mt][j][2], acc[mt][j][3]};
                *(float4*)(out + ((size_t)(b * 128 + ch) * 128 + h) * 128
                           + (w0 + mt * 16 + q * 4)) = st;
            }
        }
    }
}

// ------------------------------------------------------------------
// fused helpers
// ------------------------------------------------------------------
__device__ __forceinline__ void fs_from_n(
    int cu, const float n[9],
    const float* __restrict__ w_gw, const float* __restrict__ w_gf,
    const float* __restrict__ scp, const float* __restrict__ shp,
    float fs[9])
{
    const float p = (n[0] + n[1] + n[2] + n[3] + n[4] + n[5] + n[6] + n[7] + n[8]) * (1.f / 9.f);
    const float* gw = w_gw + cu * 9;
    const float* gf = w_gf + cu * 81;
    const float* sc = scp + cu * 9;
    const float* sh = shp + cu * 9;
    float e[9], se = 0.f;
#pragma unroll
    for (int j = 0; j < 9; ++j) { e[j] = __expf(p * gw[j]); se += e[j]; }
    const float sinv = 1.f / se;
#pragma unroll
    for (int j = 0; j < 9; ++j) {
        float cv = n[0] * gf[j * 9 + 0];
        cv = fmaf(n[1], gf[j * 9 + 1], cv); cv = fmaf(n[2], gf[j * 9 + 2], cv);
        cv = fmaf(n[3], gf[j * 9 + 3], cv); cv = fmaf(n[4], gf[j * 9 + 4], cv);
        cv = fmaf(n[5], gf[j * 9 + 5], cv); cv = fmaf(n[6], gf[j * 9 + 6], cv);
        cv = fmaf(n[7], gf[j * 9 + 7], cv); cv = fmaf(n[8], gf[j * 9 + 8], cv);
        float f = fmaf(cv, sc[j], sh[j]);
        fs[j] = fmaxf(f, 0.f) * (e[j] * sinv);
    }
}

__device__ __forceinline__ void pack_into(unsigned* pk, int ci, const float fs[9], float& carry)
{
    const int off = 9 * ci;
    if ((ci & 1) == 0) {
#pragma unroll
        for (int t = 0; t < 4; ++t) pk[off / 2 + t] = pack2(fs[2 * t], fs[2 * t + 1]);
        carry = fs[8];
    } else {
        pk[(off - 1) / 2] = pack2(carry, fs[0]);
#pragma unroll
        for (int t = 0; t < 4; ++t) pk[(off + 1) / 2 + t] = pack2(fs[1 + 2 * t], fs[2 + 2 * t]);
    }
}

// issue all 24 row-loads (8 ch x 3 rows) up front; halo layout -> no border path
__device__ __forceinline__ void chunk_loads(
    int cbase, int lane, int h0, int w0,
    const unsigned short* __restrict__ upb, uint2 vr[8][3])
{
    const int px = lane & 7, py = lane >> 3;
    // center storage col S = w0+px+4; load base (S-1)&~1 = (w0+px+3)&~1
    const size_t rowoff = (size_t)(h0 + py) * PLROW + (size_t)((w0 + px + 3) & ~1);
#pragma unroll
    for (int ci = 0; ci < 8; ++ci) {
        const int cu = __builtin_amdgcn_readfirstlane(cbase + ci);
        const unsigned short* cb = upb + (size_t)cu * PLN + rowoff;
#pragma unroll
        for (int dy = 0; dy < 3; ++dy)
            vr[ci][dy] = *(const uint2*)(cb + dy * PLROW);
    }
}

__device__ __forceinline__ void chunk_compute(
    int cbase, int lane, const uint2 vr[8][3],
    const float* __restrict__ w_gw, const float* __restrict__ w_gf,
    const float* __restrict__ scp, const float* __restrict__ shp,
    unsigned pk[36])
{
    const unsigned sh = (lane & 1) ? 0u : 16u;   // S odd (px odd): cols at 0..2; S even: 1..3
    float carry = 0.f;
#pragma unroll
    for (int ci = 0; ci < 8; ++ci) {
        const int cu = __builtin_amdgcn_readfirstlane(cbase + ci);
        float n[9];
#pragma unroll
        for (int dy = 0; dy < 3; ++dy) {
            const uint2 vv = vr[ci][dy];
            unsigned long long t = (((unsigned long long)vv.y) << 32) | vv.x;
            t >>= sh;
            n[dy * 3 + 0] = __uint_as_float((unsigned)t << 16);
            n[dy * 3 + 1] = __uint_as_float((unsigned)t & 0xffff0000u);
            n[dy * 3 + 2] = __uint_as_float((unsigned)(t >> 32) << 16);
        }
        float fs[9];
        fs_from_n(cu, n, w_gw, w_gf, scp, shp, fs);
        pack_into(pk, ci, fs, carry);
    }
}

template<int NSTEPS>
__device__ __forceinline__ void do_mfma(
    int base, const uint4* As, const unsigned short* __restrict__ bfw,
    int wv, int lane, f32x4 acc[2][2])
{
    const int q = lane >> 4, m = lane & 15;
    const int ntb = (wv >> 1) * 2;
    const int pt0 = (wv & 1) * 2;
#pragma unroll
    for (int ks = 0; ks < NSTEPS; ++ks) {
        short8 b0 = *(const short8*)(bfw + (size_t)(((base + ks) * 4 + ntb + 0) * 64 + lane) * 8);
        short8 b1 = *(const short8*)(bfw + (size_t)(((base + ks) * 4 + ntb + 1) * 64 + lane) * 8);
#pragma unroll
        for (int mt = 0; mt < 2; ++mt) {
            short8 a = *(const short8*)&As[(ks * 4 + q) * 64 + (pt0 + mt) * 16 + m];
            acc[mt][0] = __builtin_amdgcn_mfma_f32_16x16x32_bf16(a, b0, acc[mt][0], 0, 0, 0);
            acc[mt][1] = __builtin_amdgcn_mfma_f32_16x16x32_bf16(a, b1, acc[mt][1], 0, 0, 0);
        }
    }
}

// ------------------------------------------------------------------
// fused: XCD-swizzled, haloed up (no border path), prefetched loads,
// coord channels folded into precomputed co-field, K=576 (2x9 ks)
// ------------------------------------------------------------------
__global__ __launch_bounds__(256, 4) void fused_mfma(
    const float* __restrict__ wsp,
    const float* __restrict__ w_gw,
    const float* __restrict__ w_gf,
    const float* __restrict__ b_conv,
    float* __restrict__ out)
{
    __shared__ uint4 As[36 * 64];   // 36864 B

    const int bx = blockIdx.x;
    const int b  = bx & 7;          // batch -> XCD affinity
    const int t  = bx >> 3;
    const int w0 = (t & 15) * 8;
    const int h0 = ((t >> 4) & 15) * 8;
    const int tid = threadIdx.x, lane = tid & 63, wv = tid >> 6;

    const unsigned short* upb = (const unsigned short*)wsp + (size_t)b * 64 * PLN;
    const float* scp = wsp + SC_F;
    const float* shp = wsp + SH_F;
    const unsigned short* bfw = (const unsigned short*)wsp + BF_U16;

    f32x4 acc[2][2];
#pragma unroll
    for (int mt = 0; mt < 2; ++mt)
#pragma unroll
        for (int j = 0; j < 2; ++j) acc[mt][j] = (f32x4){0.f, 0.f, 0.f, 0.f};

    uint2 vr[8][3];
    unsigned pk[36];

    // ================= chunk 0 : channels 0..31 =================
    chunk_loads(8 * wv, lane, h0, w0, upb, vr);
    chunk_compute(8 * wv, lane, vr, w_gw, w_gf, scp, shp, pk);
#pragma unroll
    for (int kb = 0; kb < 9; ++kb)
        As[(9 * wv + kb) * 64 + lane] =
            (uint4){pk[4 * kb], pk[4 * kb + 1], pk[4 * kb + 2], pk[4 * kb + 3]};
    __syncthreads();

    // ================= chunk 1 : channels 32..63 =================
    chunk_loads(32 + 8 * wv, lane, h0, w0, upb, vr);   // in flight under MFMA0
    do_mfma<9>(0, As, bfw, wv, lane, acc);
    chunk_compute(32 + 8 * wv, lane, vr, w_gw, w_gf, scp, shp, pk);
    __syncthreads();   // all waves done reading As (chunk-0 MFMA)
#pragma unroll
    for (int kb = 0; kb < 9; ++kb)
        As[(9 * wv + kb) * 64 + lane] =
            (uint4){pk[4 * kb], pk[4 * kb + 1], pk[4 * kb + 2], pk[4 * kb + 3]};
    __syncthreads();
    do_mfma<9>(9, As, bfw, wv, lane, acc);

    // ================= epilogue: + bias + coord field, float4 stores =================
    const int q = lane >> 4, m = lane & 15;
    const int ntb = (wv >> 1) * 2, pt0 = (wv & 1) * 2;
    const float* co = wsp + CO_F;
#pragma unroll
    for (int mt = 0; mt < 2; ++mt)
#pragma unroll
        for (int j = 0; j < 2; ++j) {
            const int oc = (ntb + j) * 16 + m;
            const int ch = (oc & 1) ? (64 + (oc >> 1)) : (oc >> 1);
            const int row = h0 + (pt0 + mt) * 2 + (q >> 1);
            const int col = w0 + (q & 1) * 4;
            const size_t pix = (size_t)row * 128 + col;
            const float4 cv = *(const float4*)(co + (size_t)oc * 16384 + pix);
            const float bias = b_conv[oc];
            float4 st = { acc[mt][j][0] + bias + cv.x,
                          acc[mt][j][1] + bias + cv.y,
                          acc[mt][j][2] + bias + cv.z,
                          acc[mt][j][3] + bias + cv.w };
            *(float4*)(out + (size_t)(b * 128 + ch) * 16384 + pix) = st;
        }
}

// ------------------------------------------------------------------
extern "C" void kernel_launch(void* const* d_in, const int* in_sizes, int n_in,
                              void* d_out, int out_size, void* d_ws, size_t ws_size,
                              hipStream_t stream)
{
    const float* x         = (const float*)d_in[0];
    const float* w_squeeze = (const float*)d_in[1];
    const float* w_gw      = (const float*)d_in[2];
    const float* w_gf      = (const float*)d_in[3];
    const float* gamma     = (const float*)d_in[4];
    const float* beta      = (const float*)d_in[5];
    const float* mean      = (const float*)d_in[6];
    const float* var       = (const float*)d_in[7];
    const float* w_conv    = (const float*)d_in[8];
    const float* b_conv    = (const float*)d_in[9];
    float* out = (float*)d_out;
    float* ws  = (float*)d_ws;

    prep_kernel<<<256, 256, 0, stream>>>(w_squeeze, gamma, beta, mean, var,
                                         w_gw, w_gf, w_conv, ws);
    squeeze_mfma<<<2048, 256, 0, stream>>>(x, ws, out);
    fused_mfma<<<2048, 256, 0, stream>>>(ws, w_gw, w_gf, b_conv, out);
}

// Round 3
// 318.619 us; speedup vs baseline: 1.0702x; 1.0487x over previous
//
#include <hip/hip_runtime.h>
#include <math.h>

typedef __attribute__((ext_vector_type(8))) short short8;
typedef __attribute__((ext_vector_type(4))) float f32x4;

#define CIN 66
#define BN_EPS 1e-5f

// haloed up-plane: 130 rows x 136 cols of u16
// (1-row top/bottom halo, 4-col left halo, interior cols [4,132), right pad)
// row pitch 272 B (8B-aligned); interior col w -> storage col w+4 (8B-aligned uint2 stores)
#define PLROW 136
#define PLN   17680            /* 130*136 u16 per (b,oc) plane; 512 planes = 18.1 MB */

// ---- ws layout ----
// u16   [0, 512*PLN)        up (bf16) haloed planes           (ends at float 4,526,080)
// float [CO_F, +1048576)    coord-channel output field co[64][16384] (fp32)
// u16   [BSQ_U16, +BSQ_CNT) squeeze-B fragment stream
// u16   [BF_U16, +BF_CNT)   fused-B fragment stream, PADDED K'=640 (20 ks * 4 nt)
//       k' = chunk*160 + wvv*40 + s ; s<36 -> real k = chunk*144 + wvv*36 + s ; else 0
// float [SC_F,+594) scale, [SH_F,+594) shift
// float [GW2_F,+594)  gw * log2(e)/9   (softmax exponent prefold)
// float [GF2_F,+5346) gf * bn_scale    (conv weight prefold)
#define CO_F     ((size_t)4587520)
#define BSQ_U16  ((size_t)16777216)
#define BSQ_CNT  32768                /* 8 kc * 8 nt * 64 * 8 */
#define BF_U16   (BSQ_U16 + BSQ_CNT)
#define BF_CNT   40960                /* 20 ks * 4 nt * 64 * 8 */
#define SC_F     ((size_t)8425472)
#define SH_F     (SC_F + 594)
#define GW2_F    (SH_F + 594)
#define GF2_F    (GW2_F + 594)

// precise RNE (prep only)
static __device__ __forceinline__ unsigned short f2bf(float f) {
    unsigned u = __float_as_uint(f);
    u += 0x7fffu + ((u >> 16) & 1u);
    return (unsigned short)(u >> 16);
}
// fast pack: round-half-up + v_perm_b32
static __device__ __forceinline__ unsigned pack2(float lo, float hi) {
    return __builtin_amdgcn_perm(__float_as_uint(hi) + 0x8000u,
                                 __float_as_uint(lo) + 0x8000u, 0x07060302u);
}

// ------------------------------------------------------------------
// prep: BN fold + B streams + halo zero + coord field + weight prefolds
// grid MUST be 256 blocks x 256 threads (co-field uses all 65536 threads)
// ------------------------------------------------------------------
__global__ void prep_kernel(const float* __restrict__ w_squeeze,
                            const float* __restrict__ gamma,
                            const float* __restrict__ beta,
                            const float* __restrict__ mean,
                            const float* __restrict__ var,
                            const float* __restrict__ w_gw,
                            const float* __restrict__ w_gf,
                            const float* __restrict__ w_conv,
                            float* __restrict__ ws)
{
    unsigned short* wsu = (unsigned short*)ws;
    const int tid = blockIdx.x * blockDim.x + threadIdx.x;
    const int nth = gridDim.x * blockDim.x;

    for (int idx = tid; idx < BSQ_CNT; idx += nth) {
        int j = idx & 7, lane = (idx >> 3) & 63, r = idx >> 9;
        int nt = r & 7, kc = r >> 3;
        int k = kc * 32 + ((lane >> 4) << 3) + j;
        int n = nt * 16 + (lane & 15);
        wsu[BSQ_U16 + idx] = f2bf(w_squeeze[n * 256 + k]);
    }
    // fused B stream: padded K' = 640 (4 chunks x 4 waves x 40, 36 real + 4 pad)
    for (int idx = tid; idx < BF_CNT; idx += nth) {
        int j = idx & 7, lane = (idx >> 3) & 63, r = idx >> 9;
        int nt = r & 3, ks = r >> 2;                 // ks 0..19
        int kp = ks * 32 + ((lane >> 4) << 3) + j;   // k' 0..639
        int chunk = kp / 160, rem = kp - chunk * 160;
        int wvv = rem / 40, s = rem - wvv * 40;
        int n = nt * 16 + (lane & 15);
        float v = 0.f;
        if (s < 36) v = w_conv[n * 594 + chunk * 144 + wvv * 36 + s];
        wsu[BF_U16 + idx] = f2bf(v);
    }
    for (int i = tid; i < CIN * 9; i += nth) {
        float sc = gamma[i] / sqrtf(var[i] + BN_EPS);
        ws[SC_F + i] = sc;
        ws[SH_F + i] = beta[i] - mean[i] * sc;
    }
    // softmax-exponent prefold: exp(p*gw) = exp2(sum * gw * log2e/9)
    for (int i = tid; i < CIN * 9; i += nth)
        ws[GW2_F + i] = w_gw[i] * 0.16029944573f;
    // conv-weight prefold: gf2 = gf * bn_scale  (accumulate from shift)
    for (int i = tid; i < CIN * 81; i += nth) {
        int cj = i / 9;   // = ch*9 + j
        float sc = gamma[cj] * rsqrtf(var[cj] + BN_EPS);
        ws[GF2_F + i] = w_gf[i] * sc;
    }
    // zero halo of all 512 planes: 648 u32 per plane
    for (int idx = tid; idx < 512 * 648; idx += nth) {
        int plane = idx / 648, r = idx - plane * 648;
        unsigned* pb = (unsigned*)(wsu + (size_t)plane * PLN);
        if (r < 68)       pb[r] = 0u;
        else if (r < 136) pb[8772 + (r - 68)] = 0u;
        else {
            int rr = (r - 136) >> 2, k = (r - 136) & 3;
            pb[(rr + 1) * 68 + (k < 2 ? k : 64 + k)] = 0u;
        }
    }
    // coordinate-channel contribution field (input-independent, exact fp32)
    if (tid < 65536) {
        const int pix = tid & 16383;
        const int g   = tid >> 14;
        const int h = pix >> 7, w = pix & 127;
        float fsA[9], fsB[9];
#pragma unroll
        for (int c = 0; c < 2; ++c) {
            const int cu = 64 + c;
            float n[9];
#pragma unroll
            for (int dy = 0; dy < 3; ++dy)
#pragma unroll
                for (int dx = 0; dx < 3; ++dx) {
                    const int gy = h - 1 + dy, gx = w - 1 + dx;
                    const bool ok = ((unsigned)gy < 128u) & ((unsigned)gx < 128u);
                    const float v = (c == 0) ? (gx * (2.f / 127.f) - 1.f)
                                             : (gy * (2.f / 127.f) - 1.f);
                    n[dy * 3 + dx] = ok ? v : 0.f;
                }
            const float p = (n[0]+n[1]+n[2]+n[3]+n[4]+n[5]+n[6]+n[7]+n[8]) * (1.f/9.f);
            const float* gw = w_gw + cu * 9;
            const float* gf = w_gf + cu * 81;
            float e[9], se = 0.f;
#pragma unroll
            for (int j = 0; j < 9; ++j) { e[j] = __expf(p * gw[j]); se += e[j]; }
            const float sinv = 1.f / se;
            float* fs = c ? fsB : fsA;
#pragma unroll
            for (int j = 0; j < 9; ++j) {
                float cv = 0.f;
#pragma unroll
                for (int i = 0; i < 9; ++i) cv = fmaf(n[i], gf[j * 9 + i], cv);
                const float sc = gamma[cu * 9 + j] / sqrtf(var[cu * 9 + j] + BN_EPS);
                const float sh = beta[cu * 9 + j] - mean[cu * 9 + j] * sc;
                const float f = fmaf(cv, sc, sh);
                fs[j] = fmaxf(f, 0.f) * (e[j] * sinv);
            }
        }
#pragma unroll 1
        for (int oc = g * 16; oc < g * 16 + 16; ++oc) {
            const float* wc = w_conv + oc * 594;
            float s = 0.f;
#pragma unroll
            for (int j = 0; j < 9; ++j)
                s = fmaf(fsA[j], wc[576 + j], fmaf(fsB[j], wc[585 + j], s));
            ws[CO_F + (size_t)oc * 16384 + pix] = s;
        }
    }
}

// ------------------------------------------------------------------
// squeeze: space-to-depth + 1x1 conv as bf16 MFMA GEMM  (unchanged from R2)
// ------------------------------------------------------------------
__global__ __launch_bounds__(256, 4) void squeeze_mfma(
    const float* __restrict__ x,
    float* __restrict__ wsp,
    float* __restrict__ out)
{
    __shared__ uint4 As[32 * 64];   // 32768 B

    const int bx  = blockIdx.x;
    const int b   = bx & 7;         // batch -> XCD affinity
    const int pos = bx >> 3;        // 0..255
    const int h   = pos >> 1;
    const int w0  = (pos & 1) * 64;
    const int tid  = threadIdx.x;
    const int lane = tid & 63;
    const int wv   = tid >> 6;
    const int oct = tid >> 5;       // 0..7
    const int pp  = tid & 31;       // pixel pair

    float4 v[2][8];
#pragma unroll
    for (int gy = 0; gy < 2; ++gy)
#pragma unroll
        for (int i = 0; i < 8; ++i)
            v[gy][i] = *(const float4*)(x +
                (size_t)(b * 64 + oct * 8 + i) * 65536 +
                (2 * h + gy) * 256 + 2 * w0 + 4 * pp);

#pragma unroll
    for (int gy = 0; gy < 2; ++gy)
#pragma unroll
        for (int gx = 0; gx < 2; ++gx)
#pragma unroll
            for (int p = 0; p < 2; ++p) {
                const int comp = p * 2 + gx;
                uint4 u;
                u.x = pack2(((const float*)&v[gy][0])[comp], ((const float*)&v[gy][1])[comp]);
                u.y = pack2(((const float*)&v[gy][2])[comp], ((const float*)&v[gy][3])[comp]);
                u.z = pack2(((const float*)&v[gy][4])[comp], ((const float*)&v[gy][5])[comp]);
                u.w = pack2(((const float*)&v[gy][6])[comp], ((const float*)&v[gy][7])[comp]);
                As[((gy + 2 * gx) * 8 + oct) * 64 + 2 * pp + p] = u;
            }

    const unsigned short* bsq = (const unsigned short*)wsp + BSQ_U16;
    short8 b0 = *(const short8*)(bsq + (size_t)((2 * wv + 0) * 64 + lane) * 8);
    short8 b1 = *(const short8*)(bsq + (size_t)((2 * wv + 1) * 64 + lane) * 8);

    __syncthreads();

    const int q = lane >> 4, m = lane & 15;
    f32x4 acc[4][2];
#pragma unroll
    for (int mt = 0; mt < 4; ++mt)
#pragma unroll
        for (int j = 0; j < 2; ++j) acc[mt][j] = (f32x4){0.f, 0.f, 0.f, 0.f};

#pragma unroll
    for (int ks = 0; ks < 8; ++ks) {
        short8 nb0, nb1;
        if (ks < 7) {
            nb0 = *(const short8*)(bsq + (size_t)(((ks + 1) * 8 + 2 * wv + 0) * 64 + lane) * 8);
            nb1 = *(const short8*)(bsq + (size_t)(((ks + 1) * 8 + 2 * wv + 1) * 64 + lane) * 8);
        }
#pragma unroll
        for (int mt = 0; mt < 4; ++mt) {
            short8 a = *(const short8*)&As[(ks * 4 + q) * 64 + mt * 16 + m];
            acc[mt][0] = __builtin_amdgcn_mfma_f32_16x16x32_bf16(a, b0, acc[mt][0], 0, 0, 0);
            acc[mt][1] = __builtin_amdgcn_mfma_f32_16x16x32_bf16(a, b1, acc[mt][1], 0, 0, 0);
        }
        if (ks < 7) { b0 = nb0; b1 = nb1; }
    }

    if (wv < 2) {
        unsigned short* upw = (unsigned short*)wsp;
#pragma unroll
        for (int j = 0; j < 2; ++j) {
            const int oc = (2 * wv + j) * 16 + m;
#pragma unroll
            for (int mt = 0; mt < 4; ++mt) {
                uint2 st;
                st.x = pack2(acc[mt][j][0], acc[mt][j][1]);
                st.y = pack2(acc[mt][j][2], acc[mt][j][3]);
                *(uint2*)(upw + (size_t)(b * 64 + oc) * PLN + (size_t)(h + 1) * PLROW
                          + (w0 + mt * 16 + q * 4 + 4)) = st;
            }
        }
    } else {
#pragma unroll
        for (int j = 0; j < 2; ++j) {
            const int oc = (2 * wv + j) * 16 + m;
            const int lc = oc - 64;
            const int ch = (lc & 1) ? (96 + ((lc - 1) >> 1)) : (32 + (lc >> 1));
#pragma unroll
            for (int mt = 0; mt < 4; ++mt) {
                float4 st = {acc[mt][j][0], acc[mt][j][1], acc[mt][j][2], acc[mt][j][3]};
                *(float4*)(out + ((size_t)(b * 128 + ch) * 128 + h) * 128
                           + (w0 + mt * 16 + q * 4)) = st;
            }
        }
    }
}

// ------------------------------------------------------------------
// fused helpers (v3: prefolded weights, 4-channel strips)
// ------------------------------------------------------------------
__device__ __forceinline__ void fs_from_n2(
    int cu, const float n[9],
    const float* __restrict__ gw2, const float* __restrict__ gf2,
    const float* __restrict__ shp, float fs[9])
{
    const float s = ((n[0] + n[1]) + (n[2] + n[3])) + ((n[4] + n[5]) + (n[6] + n[7])) + n[8];
    const float* gw = gw2 + cu * 9;
    const float* gf = gf2 + cu * 81;
    const float* sh = shp + cu * 9;
    float e[9], se = 0.f;
#pragma unroll
    for (int j = 0; j < 9; ++j) { e[j] = __builtin_amdgcn_exp2f(s * gw[j]); se += e[j]; }
    const float sinv = __builtin_amdgcn_rcpf(se);
#pragma unroll
    for (int j = 0; j < 9; ++j) {
        float cv = sh[j];
#pragma unroll
        for (int i = 0; i < 9; ++i) cv = fmaf(n[i], gf[j * 9 + i], cv);
        fs[j] = fmaxf(cv, 0.f) * (e[j] * sinv);
    }
}

__device__ __forceinline__ void pack_into(unsigned* pk, int ci, const float fs[9], float& carry)
{
    const int off = 9 * ci;
    if ((ci & 1) == 0) {
#pragma unroll
        for (int t = 0; t < 4; ++t) pk[off / 2 + t] = pack2(fs[2 * t], fs[2 * t + 1]);
        carry = fs[8];
    } else {
        pk[(off - 1) / 2] = pack2(carry, fs[0]);
#pragma unroll
        for (int t = 0; t < 4; ++t) pk[(off + 1) / 2 + t] = pack2(fs[1 + 2 * t], fs[2 + 2 * t]);
    }
}

// 12 row-loads (4 ch x 3 rows) issued up front
__device__ __forceinline__ void chunk_loads4(
    int cbase, int lane, int h0, int w0,
    const unsigned short* __restrict__ upb, uint2 vr[4][3])
{
    const int px = lane & 7, py = lane >> 3;
    const size_t rowoff = (size_t)(h0 + py) * PLROW + (size_t)((w0 + px + 3) & ~1);
#pragma unroll
    for (int ci = 0; ci < 4; ++ci) {
        const int cu = __builtin_amdgcn_readfirstlane(cbase + ci);
        const unsigned short* cb = upb + (size_t)cu * PLN + rowoff;
#pragma unroll
        for (int dy = 0; dy < 3; ++dy)
            vr[ci][dy] = *(const uint2*)(cb + dy * PLROW);
    }
}

// 4 channels -> pk[0..17] bf16-packed, pk[18..19] zero pad
__device__ __forceinline__ void chunk_compute4(
    int cbase, int lane, const uint2 vr[4][3],
    const float* __restrict__ gw2, const float* __restrict__ gf2,
    const float* __restrict__ shp, unsigned pk[20])
{
    const unsigned shf = (lane & 1) ? 0u : 16u;
    float carry = 0.f;
#pragma unroll
    for (int ci = 0; ci < 4; ++ci) {
        const int cu = __builtin_amdgcn_readfirstlane(cbase + ci);
        float n[9];
#pragma unroll
        for (int dy = 0; dy < 3; ++dy) {
            const uint2 vv = vr[ci][dy];
            unsigned long long t = (((unsigned long long)vv.y) << 32) | vv.x;
            t >>= shf;
            n[dy * 3 + 0] = __uint_as_float((unsigned)t << 16);
            n[dy * 3 + 1] = __uint_as_float((unsigned)t & 0xffff0000u);
            n[dy * 3 + 2] = __uint_as_float((unsigned)(t >> 32) << 16);
        }
        float fs[9];
        fs_from_n2(cu, n, gw2, gf2, shp, fs);
        pack_into(pk, ci, fs, carry);
    }
    pk[18] = 0u; pk[19] = 0u;
}

// one padded chunk: 5 k-steps
__device__ __forceinline__ void do_mfma5(
    int bbase, const uint4* As, const unsigned short* __restrict__ bfw,
    int wv, int lane, f32x4 acc[2][2])
{
    const int q = lane >> 4, m = lane & 15;
    const int ntb = (wv >> 1) * 2;
    const int pt0 = (wv & 1) * 2;
#pragma unroll
    for (int ks = 0; ks < 5; ++ks) {
        short8 b0 = *(const short8*)(bfw + (size_t)(((bbase + ks) * 4 + ntb + 0) * 64 + lane) * 8);
        short8 b1 = *(const short8*)(bfw + (size_t)(((bbase + ks) * 4 + ntb + 1) * 64 + lane) * 8);
#pragma unroll
        for (int mt = 0; mt < 2; ++mt) {
            short8 a = *(const short8*)&As[(ks * 4 + q) * 64 + (pt0 + mt) * 16 + m];
            acc[mt][0] = __builtin_amdgcn_mfma_f32_16x16x32_bf16(a, b0, acc[mt][0], 0, 0, 0);
            acc[mt][1] = __builtin_amdgcn_mfma_f32_16x16x32_bf16(a, b1, acc[mt][1], 0, 0, 0);
        }
    }
}

// ------------------------------------------------------------------
// fused v3: 4 padded chunks (K'=640), 20-row LDS (20480 B), high occupancy
// ------------------------------------------------------------------
__global__ __launch_bounds__(256, 6) void fused_mfma(
    const float* __restrict__ wsp,
    const float* __restrict__ b_conv,
    float* __restrict__ out)
{
    __shared__ uint4 As[20 * 64];   // 20480 B

    const int bx = blockIdx.x;
    const int b  = bx & 7;          // batch -> XCD affinity
    const int t  = bx >> 3;
    const int w0 = (t & 15) * 8;
    const int h0 = ((t >> 4) & 15) * 8;
    const int tid = threadIdx.x, lane = tid & 63, wv = tid >> 6;

    const unsigned short* upb = (const unsigned short*)wsp + (size_t)b * 64 * PLN;
    const float* gw2 = wsp + GW2_F;
    const float* gf2 = wsp + GF2_F;
    const float* shp = wsp + SH_F;
    const unsigned short* bfw = (const unsigned short*)wsp + BF_U16;

    f32x4 acc[2][2];
#pragma unroll
    for (int mt = 0; mt < 2; ++mt)
#pragma unroll
        for (int j = 0; j < 2; ++j) acc[mt][j] = (f32x4){0.f, 0.f, 0.f, 0.f};

    uint2 vr[4][3];
    unsigned pk[20];

    // prologue: chunk 0 (channels wv*4 .. wv*4+3)
    chunk_loads4(wv * 4, lane, h0, w0, upb, vr);
    chunk_compute4(wv * 4, lane, vr, gw2, gf2, shp, pk);
#pragma unroll
    for (int kb = 0; kb < 5; ++kb)
        As[(5 * wv + kb) * 64 + lane] =
            (uint4){pk[4 * kb], pk[4 * kb + 1], pk[4 * kb + 2], pk[4 * kb + 3]};
    __syncthreads();

#pragma unroll
    for (int c = 0; c < 4; ++c) {
        if (c < 3) chunk_loads4((c + 1) * 16 + wv * 4, lane, h0, w0, upb, vr);
        do_mfma5(c * 5, As, bfw, wv, lane, acc);
        if (c < 3) {
            chunk_compute4((c + 1) * 16 + wv * 4, lane, vr, gw2, gf2, shp, pk);
            __syncthreads();   // all waves done reading As for chunk c
#pragma unroll
            for (int kb = 0; kb < 5; ++kb)
                As[(5 * wv + kb) * 64 + lane] =
                    (uint4){pk[4 * kb], pk[4 * kb + 1], pk[4 * kb + 2], pk[4 * kb + 3]};
            __syncthreads();   // writes visible
        }
    }

    // ================= epilogue: + bias + coord field, float4 stores =================
    const int q = lane >> 4, m = lane & 15;
    const int ntb = (wv >> 1) * 2, pt0 = (wv & 1) * 2;
    const float* co = wsp + CO_F;
#pragma unroll
    for (int mt = 0; mt < 2; ++mt)
#pragma unroll
        for (int j = 0; j < 2; ++j) {
            const int oc = (ntb + j) * 16 + m;
            const int ch = (oc & 1) ? (64 + (oc >> 1)) : (oc >> 1);
            const int row = h0 + (pt0 + mt) * 2 + (q >> 1);
            const int col = w0 + (q & 1) * 4;
            const size_t pix = (size_t)row * 128 + col;
            const float4 cv = *(const float4*)(co + (size_t)oc * 16384 + pix);
            const float bias = b_conv[oc];
            float4 st = { acc[mt][j][0] + bias + cv.x,
                          acc[mt][j][1] + bias + cv.y,
                          acc[mt][j][2] + bias + cv.z,
                          acc[mt][j][3] + bias + cv.w };
            *(float4*)(out + (size_t)(b * 128 + ch) * 16384 + pix) = st;
        }
}

// ------------------------------------------------------------------
extern "C" void kernel_launch(void* const* d_in, const int* in_sizes, int n_in,
                              void* d_out, int out_size, void* d_ws, size_t ws_size,
                              hipStream_t stream)
{
    const float* x         = (const float*)d_in[0];
    const float* w_squeeze = (const float*)d_in[1];
    const float* w_gw      = (const float*)d_in[2];
    const float* w_gf      = (const float*)d_in[3];
    const float* gamma     = (const float*)d_in[4];
    const float* beta      = (const float*)d_in[5];
    const float* mean      = (const float*)d_in[6];
    const float* var       = (const float*)d_in[7];
    const float* w_conv    = (const float*)d_in[8];
    const float* b_conv    = (const float*)d_in[9];
    float* out = (float*)d_out;
    float* ws  = (float*)d_ws;

    prep_kernel<<<256, 256, 0, stream>>>(w_squeeze, gamma, beta, mean, var,
                                         w_gw, w_gf, w_conv, ws);
    squeeze_mfma<<<2048, 256, 0, stream>>>(x, ws, out);
    fused_mfma<<<2048, 256, 0, stream>>>(ws, b_conv, out);
}